// Round 12
// baseline (238.554 us; speedup 1.0000x reference)
//
#include <hip/hip_runtime.h>
#include <cmath>

typedef float  float4_t __attribute__((ext_vector_type(4)));
typedef __bf16 bf16x8   __attribute__((ext_vector_type(8)));
typedef unsigned short u16;

// fp32 -> bf16 round-to-nearest-even
__device__ __forceinline__ u16 f2bf(float f) {
    unsigned u = __float_as_uint(f);
    u += 0x7fffu + ((u >> 16) & 1u);
    return (u16)(u >> 16);
}
// fp32 -> bf16 round-half-up (2 VALU ops; <=1/2 ulp bias, used for P only)
__device__ __forceinline__ u16 f2bf_hu(float f) {
    return (u16)((__float_as_uint(f) + 0x8000u) >> 16);
}

// async global->LDS, 16B per lane. LDS dest must be wave-uniform base + lane*16.
#define GLOAD_LDS16(g, l)                                              \
    __builtin_amdgcn_global_load_lds(                                  \
        (__attribute__((address_space(1))) void*)(g),                  \
        (__attribute__((address_space(3))) void*)(l), 16, 0, 0)

// ---------------- merged cast fp32 -> bf16 for all 5 tensors ----------------
__global__ __launch_bounds__(256) void cast_all(const float* __restrict__ x,
                                                const float* __restrict__ wq,
                                                const float* __restrict__ wk,
                                                const float* __restrict__ wv,
                                                const float* __restrict__ wo,
                                                u16* __restrict__ xb, u16* __restrict__ wqb,
                                                u16* __restrict__ wkb, u16* __restrict__ wvb,
                                                u16* __restrict__ wob) {
    const int b = blockIdx.x;
    const float* src;
    u16* dst;
    int i;
    if (b < 4096)      { src = x;  dst = xb;  i = b * 256 + threadIdx.x; }
    else if (b < 8192) { src = wq; dst = wqb; i = (b - 4096) * 256 + threadIdx.x; }
    else if (b < 8448) { src = wk; dst = wkb; i = (b - 8192) * 256 + threadIdx.x; }
    else if (b < 8704) { src = wv; dst = wvb; i = (b - 8448) * 256 + threadIdx.x; }
    else               { src = wo; dst = wob; i = (b - 8704) * 256 + threadIdx.x; }
    float4 f = ((const float4*)src)[i];
    ushort4 r;
    r.x = f2bf(f.x); r.y = f2bf(f.y); r.z = f2bf(f.z); r.w = f2bf(f.w);
    ((ushort4*)dst)[i] = r;
}

// ================= GEMM core (A @ B^T, 64x64 tile, BK=64) ===================
// 16KB LDS -> 4-5 blocks/CU at N=2048 grids (occupancy-dominated regime).
// 256 threads = 4 waves in 2x2; wave-tile 32x32 (2x2 MFMA tiles).
// LDS sub-tiled [ksub][row][32], 64B rows (bank-safe for b128 frags).
template <typename EPI>
__device__ __forceinline__ void gemm64_core(const u16* __restrict__ A,
                                            const u16* __restrict__ B,
                                            int K, int bm, int bn, EPI epi) {
    __shared__ __align__(16) u16 As[2 * 64 * 32];
    __shared__ __align__(16) u16 Bs[2 * 64 * 32];
    const int tid  = threadIdx.x;
    const int lane = tid & 63, wave = tid >> 6;
    const int wm = wave >> 1, wn = wave & 1;
    const int quad = lane >> 4, l16 = lane & 15;

    float4_t acc[2][2] = {};

    for (int k0 = 0; k0 < K; k0 += 64) {
        // A/B: 512 slots of 16B each: ks=slot>>8, row=(slot&255)>>2, ch=(slot&3)*8
#pragma unroll
        for (int i = 0; i < 2; ++i) {
            const int slot = i * 256 + tid;
            const int ks = slot >> 8, win = slot & 255;
            const int row = win >> 2, ch = (win & 3) * 8;
            GLOAD_LDS16(A + (size_t)(bm + row) * K + k0 + ks * 32 + ch, &As[slot * 8]);
            GLOAD_LDS16(B + (size_t)(bn + row) * K + k0 + ks * 32 + ch, &Bs[slot * 8]);
        }
        __syncthreads();

        bf16x8 af[2][2], bfr[2][2];
#pragma unroll
        for (int ks = 0; ks < 2; ++ks) {
#pragma unroll
            for (int mi = 0; mi < 2; ++mi)
                af[ks][mi] = *(const bf16x8*)&As[ks * 2048 + (wm * 32 + mi * 16 + l16) * 32 + quad * 8];
#pragma unroll
            for (int ni = 0; ni < 2; ++ni)
                bfr[ks][ni] = *(const bf16x8*)&Bs[ks * 2048 + (wn * 32 + ni * 16 + l16) * 32 + quad * 8];
        }
#pragma unroll
        for (int mi = 0; mi < 2; ++mi)
#pragma unroll
            for (int ni = 0; ni < 2; ++ni) {
                acc[mi][ni] = __builtin_amdgcn_mfma_f32_16x16x32_bf16(
                    af[0][mi], bfr[0][ni], acc[mi][ni], 0, 0, 0);
                acc[mi][ni] = __builtin_amdgcn_mfma_f32_16x16x32_bf16(
                    af[1][mi], bfr[1][ni], acc[mi][ni], 0, 0, 0);
            }
        __syncthreads();
    }

#pragma unroll
    for (int mi = 0; mi < 2; ++mi) {
        const int row = bm + wm * 32 + mi * 16 + quad * 4;
#pragma unroll
        for (int ni = 0; ni < 2; ++ni) {
            const int col = bn + wn * 32 + ni * 16 + l16;
#pragma unroll
            for (int r = 0; r < 4; ++r) epi(row + r, col, acc[mi][ni][r]);
        }
    }
}

// Fused QKV projection: B rows = [Wq(2048) | Wk(128) | Wv(128)], N=2304.
// Q gets (1/sqrt(128))*log2(e) folded in (attention uses exp2).
__global__ __launch_bounds__(256) void gemm_qkv(const u16* __restrict__ A,
                                                const u16* __restrict__ B,
                                                u16* __restrict__ qb,
                                                u16* __restrict__ kb,
                                                u16* __restrict__ vtb) {
    gemm64_core(A, B, 2048, blockIdx.x * 64, blockIdx.y * 64,
                [=](int row, int col, float v) {
                    if (col < 2048)
                        qb[(size_t)row * 2048 + col] = f2bf(v * 0.1275174313451427f);
                    else if (col < 2176)
                        kb[(size_t)row * 128 + (col - 2048)] = f2bf(v);
                    else
                        vtb[(size_t)(col - 2176) * 2048 + row] = f2bf(v);
                });
}

__global__ __launch_bounds__(256) void gemm_out(const u16* __restrict__ A,
                                                const u16* __restrict__ B,
                                                float* __restrict__ C) {
    gemm64_core(A, B, 2048, blockIdx.x * 64, blockIdx.y * 64,
                [=](int row, int col, float v) {
                    C[(size_t)row * 2048 + col] = v;
                });
}

// ---------------- MQA flash attention, split-K=2, PV software-pipelined -----
// Q:[2048,2048] bf16 pre-scaled by (1/sqrt(128))*log2e; K:[2048,128]; Vt:[128,2048].
// Block = 128 q x 1 head x 1 key-half; 4 waves x 32 q; 32 keys/step.
// Grid (16,16,2) = 512 blocks. ~26KB LDS.
// PV runs ONE STEP LATE: pa/vf of step s-1 held in registers across the barrier,
// so PV(s-1) (16 independent MFMAs) interleaves with QK(s)'s dependent chains.
// Deferred softmax: P = exp2(s) (scores bounded); fp32 partials + Lsum per split.
__global__ __launch_bounds__(256) void mqa_attn(const u16* __restrict__ Q,
                                                const u16* __restrict__ Kmat,
                                                const u16* __restrict__ Vt,
                                                float* __restrict__ Oacc0,
                                                float* __restrict__ Oacc1,
                                                float* __restrict__ Lsum) {
    __shared__ __align__(16) u16 Ks[4 * 32 * 32];   // [d-chunk kb4][key32][32 d]
    __shared__ __align__(16) u16 Vts[128 * 32];     // [d][32 keys]
    __shared__ __align__(16) u16 Ps[4][32 * 40];    // per-wave P, row stride 40
    const int tid  = threadIdx.x;
    const int wave = tid >> 6, lane = tid & 63;
    const int quad = lane >> 4, l16 = lane & 15;
    const int h     = blockIdx.y;
    const int ks    = blockIdx.z;
    const int qbase = blockIdx.x * 128 + wave * 32;
    const int kbase = ks * 1024;

    // Q fragments: 2 mt x 4 d-chunks, resident all kernel
    bf16x8 qf[2][4];
#pragma unroll
    for (int mt = 0; mt < 2; ++mt)
#pragma unroll
        for (int kb4 = 0; kb4 < 4; ++kb4)
            qf[mt][kb4] = *(const bf16x8*)(Q + (size_t)(qbase + mt * 16 + l16) * 2048 +
                                           h * 128 + kb4 * 32 + quad * 8);

    float4_t acc[2][8];
#pragma unroll
    for (int mt = 0; mt < 2; ++mt)
#pragma unroll
        for (int nt = 0; nt < 8; ++nt) acc[mt][nt] = (float4_t){0.f, 0.f, 0.f, 0.f};
    float lsum[8] = {};   // [mt*4 + r]

    bf16x8 pa_prev[2];    // P A-frags of step s-1 (held across barrier)
    bf16x8 vf_prev[8];    // V B-frags of step s-1

    u16* pb = Ps[wave];

    for (int s = 0; s < 32; ++s) {
        const int k0 = kbase + s * 32;
        // stage K tile: 512 slots -> (kb4 = slot>>7, key = (slot&127)>>2, ch)
#pragma unroll
        for (int i = 0; i < 2; ++i) {
            const int slot = i * 256 + tid;
            const int kb4 = slot >> 7, win = slot & 127;
            const int row = win >> 2, ch = (win & 3) * 8;
            GLOAD_LDS16(Kmat + (size_t)(k0 + row) * 128 + kb4 * 32 + ch, &Ks[slot * 8]);
        }
        // stage V tile: 512 slots -> (d = slot>>2, ch)
#pragma unroll
        for (int i = 0; i < 2; ++i) {
            const int slot = i * 256 + tid;
            const int d = slot >> 2, ch = (slot & 3) * 8;
            GLOAD_LDS16(Vt + (size_t)d * 2048 + k0 + ch, &Vts[slot * 8]);
        }
        __syncthreads();

        // ---- PV(s-1): 16 independent MFMAs, interleaves with QK(s) below ----
        if (s > 0) {
#pragma unroll
            for (int nt = 0; nt < 8; ++nt) {
                acc[0][nt] = __builtin_amdgcn_mfma_f32_16x16x32_bf16(pa_prev[0], vf_prev[nt], acc[0][nt], 0, 0, 0);
                acc[1][nt] = __builtin_amdgcn_mfma_f32_16x16x32_bf16(pa_prev[1], vf_prev[nt], acc[1][nt], 0, 0, 0);
            }
        }

        // ---- S = Q K^T over 32 keys (2 col-tiles of 16); P = exp2(S) ----
#pragma unroll
        for (int ct = 0; ct < 2; ++ct) {
            float4_t s0 = (float4_t){0.f, 0.f, 0.f, 0.f};
            float4_t s1 = (float4_t){0.f, 0.f, 0.f, 0.f};
#pragma unroll
            for (int kb4 = 0; kb4 < 4; ++kb4) {
                bf16x8 kf = *(const bf16x8*)&Ks[kb4 * 1024 + (ct * 16 + l16) * 32 + quad * 8];
                s0 = __builtin_amdgcn_mfma_f32_16x16x32_bf16(qf[0][kb4], kf, s0, 0, 0, 0);
                s1 = __builtin_amdgcn_mfma_f32_16x16x32_bf16(qf[1][kb4], kf, s1, 0, 0, 0);
            }
#pragma unroll
            for (int r = 0; r < 4; ++r) {
                const float e0 = exp2f(s0[r]);
                const float e1 = exp2f(s1[r]);
                lsum[r]     += e0;
                lsum[4 + r] += e1;
                pb[(quad * 4 + r) * 40 + ct * 16 + l16]      = f2bf_hu(e0);
                pb[(16 + quad * 4 + r) * 40 + ct * 16 + l16] = f2bf_hu(e1);
            }
        }
        // read pa(s) (own-wave RAW, short lgkm wait) and vf(s) into registers
#pragma unroll
        for (int mt = 0; mt < 2; ++mt)
            pa_prev[mt] = *(const bf16x8*)&pb[(mt * 16 + l16) * 40 + quad * 8];
#pragma unroll
        for (int nt = 0; nt < 8; ++nt)
            vf_prev[nt] = *(const bf16x8*)&Vts[(nt * 16 + l16) * 32 + quad * 8];
        __syncthreads();   // all reads of tile s done; next stage may overwrite
    }

    // epilogue: final PV
#pragma unroll
    for (int nt = 0; nt < 8; ++nt) {
        acc[0][nt] = __builtin_amdgcn_mfma_f32_16x16x32_bf16(pa_prev[0], vf_prev[nt], acc[0][nt], 0, 0, 0);
        acc[1][nt] = __builtin_amdgcn_mfma_f32_16x16x32_bf16(pa_prev[1], vf_prev[nt], acc[1][nt], 0, 0, 0);
    }

    // write unnormalized fp32 partials + per-row sum partials (written once; no init)
    float* __restrict__ Op = ks ? Oacc1 : Oacc0;
#pragma unroll
    for (int mt = 0; mt < 2; ++mt)
#pragma unroll
        for (int r = 0; r < 4; ++r) {
            const int row = qbase + mt * 16 + quad * 4 + r;
            const size_t base = ((size_t)h * 2048 + row) * 128;
            float lrow = lsum[mt * 4 + r];
#pragma unroll
            for (int off = 1; off < 16; off <<= 1) lrow += __shfl_xor(lrow, off);
            if (l16 == 0) Lsum[(size_t)ks * 32768 + h * 2048 + row] = lrow;
#pragma unroll
            for (int nt = 0; nt < 8; ++nt)
                Op[base + nt * 16 + l16] = acc[mt][nt][r];
        }
}

// combine: attn[q][h*128+d] = (O0+O1)/(L0+L1), bf16. One float4 per thread.
__global__ __launch_bounds__(256) void attn_combine(const float* __restrict__ O0,
                                                    const float* __restrict__ O1,
                                                    const float* __restrict__ L,
                                                    u16* __restrict__ attn) {
    const int f = blockIdx.x * 256 + threadIdx.x;  // [0, 1M)
    const int d4 = f & 31, h = (f >> 5) & 15, q = f >> 9;
    const int li = h * 2048 + q;
    const float inv = 1.0f / (L[li] + L[32768 + li]);
    const int oi = li * 32 + d4;
    const float4 a = ((const float4*)O0)[oi];
    const float4 b = ((const float4*)O1)[oi];
    ushort4 r;
    r.x = f2bf((a.x + b.x) * inv);
    r.y = f2bf((a.y + b.y) * inv);
    r.z = f2bf((a.z + b.z) * inv);
    r.w = f2bf((a.w + b.w) * inv);
    ((ushort4*)attn)[f] = r;
}

// ---------------- orchestration ----------------
extern "C" void kernel_launch(void* const* d_in, const int* in_sizes, int n_in,
                              void* d_out, int out_size, void* d_ws, size_t ws_size,
                              hipStream_t stream) {
    const float* x  = (const float*)d_in[0];
    const float* Wq = (const float*)d_in[1];
    const float* Wk = (const float*)d_in[2];
    const float* Wv = (const float*)d_in[3];
    const float* Wo = (const float*)d_in[4];
    float* out = (float*)d_out;

    // Wqb/Wkb/Wvb contiguous: together a 2304x2048 bf16 B matrix for gemm_qkv.
    // Overlays (stream-ordered, deterministic):
    //   Oacc0: [0,16MB)  -- xb+Wqb dead after gemm_qkv
    //   Oacc1: [42,58MB) -- fresh scratch; Lsum at [58,58.5MB). Peak 58.5MB.
    u16* ws   = (u16*)d_ws;
    u16* xb   = ws;                        // 2048x2048 bf16
    u16* Wqb  = xb  + (4 << 20);           // 2048x2048
    u16* Wkb  = Wqb + (4 << 20);           // 128x2048
    u16* Wvb  = Wkb + (256 << 10);         // 128x2048
    u16* Wob  = Wvb + (256 << 10);         // 2048x2048
    u16* qb   = Wob + (4 << 20);           // 2048x2048 (pre-scaled)
    u16* kb   = qb  + (4 << 20);           // 2048x128
    u16* vtb  = kb  + (256 << 10);         // 128x2048 (V^T)
    u16* attn = vtb + (256 << 10);         // 2048x2048 bf16, ends at 42 MB
    float* Oacc0 = (float*)ws;             // 16 MB
    float* Oacc1 = (float*)(attn + (4 << 20));  // 16 MB at [42,58)
    float* Lsum  = Oacc1 + (4 << 20);      // 2 x 32768 fp32

    cast_all<<<12800, 256, 0, stream>>>(x, Wq, Wk, Wv, Wo, xb, Wqb, Wkb, Wvb, Wob);

    gemm_qkv<<<dim3(32, 36), 256, 0, stream>>>(xb, Wqb, qb, kb, vtb);
    mqa_attn<<<dim3(16, 16, 2), 256, 0, stream>>>(qb, kb, vtb, Oacc0, Oacc1, Lsum);
    attn_combine<<<4096, 256, 0, stream>>>(Oacc0, Oacc1, Lsum, attn);
    gemm_out<<<dim3(32, 32), 256, 0, stream>>>(attn, Wob, out);
}

// Round 13
// 226.675 us; speedup vs baseline: 1.0524x; 1.0524x over previous
//
#include <hip/hip_runtime.h>
#include <cmath>

typedef float  float4_t __attribute__((ext_vector_type(4)));
typedef __bf16 bf16x8   __attribute__((ext_vector_type(8)));
typedef unsigned short u16;

// fp32 -> bf16 round-to-nearest-even
__device__ __forceinline__ u16 f2bf(float f) {
    unsigned u = __float_as_uint(f);
    u += 0x7fffu + ((u >> 16) & 1u);
    return (u16)(u >> 16);
}
// fp32 -> bf16 round-half-up (2 VALU ops; <=1/2 ulp bias, used for P only)
__device__ __forceinline__ u16 f2bf_hu(float f) {
    return (u16)((__float_as_uint(f) + 0x8000u) >> 16);
}

// async global->LDS, 16B per lane. LDS dest must be wave-uniform base + lane*16.
#define GLOAD_LDS16(g, l)                                              \
    __builtin_amdgcn_global_load_lds(                                  \
        (__attribute__((address_space(1))) void*)(g),                  \
        (__attribute__((address_space(3))) void*)(l), 16, 0, 0)

// Chunk swizzle: global chunk c of row r is stored at LDS chunk (c + (r>>1))&3.
// Staging picks global chunk cg = (cs - (r>>1))&3 for LDS slot chunk cs; frag
// reads use chunk ((quad + (r>>1))&3). Turns 8-way b128 read conflicts into
// 2-way (free tier, m136). Rows stay 64B so global coalescing is unchanged.
__device__ __forceinline__ int sw_st(int cs, int row) { return ((cs - (row >> 1)) & 3) * 8; }
__device__ __forceinline__ int sw_rd(int quad, int row) { return (((quad + (row >> 1)) & 3)) * 8; }

// ---------------- merged cast fp32 -> bf16 for all 5 tensors ----------------
__global__ __launch_bounds__(256) void cast_all(const float* __restrict__ x,
                                                const float* __restrict__ wq,
                                                const float* __restrict__ wk,
                                                const float* __restrict__ wv,
                                                const float* __restrict__ wo,
                                                u16* __restrict__ xb, u16* __restrict__ wqb,
                                                u16* __restrict__ wkb, u16* __restrict__ wvb,
                                                u16* __restrict__ wob) {
    const int b = blockIdx.x;
    const float* src;
    u16* dst;
    int i;
    if (b < 4096)      { src = x;  dst = xb;  i = b * 256 + threadIdx.x; }
    else if (b < 8192) { src = wq; dst = wqb; i = (b - 4096) * 256 + threadIdx.x; }
    else if (b < 8448) { src = wk; dst = wkb; i = (b - 8192) * 256 + threadIdx.x; }
    else if (b < 8704) { src = wv; dst = wvb; i = (b - 8448) * 256 + threadIdx.x; }
    else               { src = wo; dst = wob; i = (b - 8704) * 256 + threadIdx.x; }
    float4 f = ((const float4*)src)[i];
    ushort4 r;
    r.x = f2bf(f.x); r.y = f2bf(f.y); r.z = f2bf(f.z); r.w = f2bf(f.w);
    ((ushort4*)dst)[i] = r;
}

// ================= GEMM core (A @ B^T, 64x128 tile, BK=64, swizzled) ========
// LDS sub-tiled [ksub][row][32], 64B rows; chunk-swizzled to kill read conflicts.
// 24KB LDS, 256 threads = 4 waves; each wave: 64 M-rows x 32 N-cols, 16 MFMA/step.
template <typename EPI>
__device__ __forceinline__ void gemm_core(const u16* __restrict__ A,
                                          const u16* __restrict__ B,
                                          int K, int bm, int bn, EPI epi) {
    __shared__ __align__(16) u16 As[2 * 64 * 32];
    __shared__ __align__(16) u16 Bs[2 * 128 * 32];
    const int tid  = threadIdx.x;
    const int lane = tid & 63, wave = tid >> 6;
    const int quad = lane >> 4, l16 = lane & 15;

    float4_t acc[4][2] = {};

    for (int k0 = 0; k0 < K; k0 += 64) {
        // A: 512 slots of 16B: ks=slot>>8, row=(slot&255)>>2, cs=slot&3 (swizzled)
#pragma unroll
        for (int i = 0; i < 2; ++i) {
            const int slot = i * 256 + tid;
            const int ks = slot >> 8, win = slot & 255;
            const int row = win >> 2;
            GLOAD_LDS16(A + (size_t)(bm + row) * K + k0 + ks * 32 + sw_st(win & 3, row),
                        &As[slot * 8]);
        }
        // B: 1024 slots
#pragma unroll
        for (int i = 0; i < 4; ++i) {
            const int slot = i * 256 + tid;
            const int ks = slot >> 9, win = slot & 511;
            const int row = win >> 2;
            GLOAD_LDS16(B + (size_t)(bn + row) * K + k0 + ks * 32 + sw_st(win & 3, row),
                        &Bs[slot * 8]);
        }
        __syncthreads();

        bf16x8 af[2][4], bfr[2][2];
#pragma unroll
        for (int ks = 0; ks < 2; ++ks) {
#pragma unroll
            for (int mi = 0; mi < 4; ++mi) {
                const int rw = mi * 16 + l16;
                af[ks][mi] = *(const bf16x8*)&As[ks * 2048 + rw * 32 + sw_rd(quad, rw)];
            }
#pragma unroll
            for (int ni = 0; ni < 2; ++ni) {
                const int rw = wave * 32 + ni * 16 + l16;
                bfr[ks][ni] = *(const bf16x8*)&Bs[ks * 4096 + rw * 32 + sw_rd(quad, rw)];
            }
        }
#pragma unroll
        for (int mi = 0; mi < 4; ++mi)
#pragma unroll
            for (int ni = 0; ni < 2; ++ni) {
                acc[mi][ni] = __builtin_amdgcn_mfma_f32_16x16x32_bf16(
                    af[0][mi], bfr[0][ni], acc[mi][ni], 0, 0, 0);
                acc[mi][ni] = __builtin_amdgcn_mfma_f32_16x16x32_bf16(
                    af[1][mi], bfr[1][ni], acc[mi][ni], 0, 0, 0);
            }
        __syncthreads();
    }

#pragma unroll
    for (int mi = 0; mi < 4; ++mi) {
        const int row = bm + mi * 16 + quad * 4;
#pragma unroll
        for (int ni = 0; ni < 2; ++ni) {
            const int col = bn + wave * 32 + ni * 16 + l16;
#pragma unroll
            for (int r = 0; r < 4; ++r) epi(row + r, col, acc[mi][ni][r]);
        }
    }
}

// Fused QKV projection: B rows = [Wq(2048) | Wk(128) | Wv(128)], N=2304.
// Q gets (1/sqrt(128))*log2(e) folded in (attention uses exp2).
__global__ __launch_bounds__(256) void gemm_qkv(const u16* __restrict__ A,
                                                const u16* __restrict__ B,
                                                u16* __restrict__ qb,
                                                u16* __restrict__ kb,
                                                u16* __restrict__ vtb) {
    gemm_core(A, B, 2048, blockIdx.x * 64, blockIdx.y * 128,
              [=](int row, int col, float v) {
                  if (col < 2048)
                      qb[(size_t)row * 2048 + col] = f2bf(v * 0.1275174313451427f);
                  else if (col < 2176)
                      kb[(size_t)row * 128 + (col - 2048)] = f2bf(v);
                  else
                      vtb[(size_t)(col - 2176) * 2048 + row] = f2bf(v);
              });
}

__global__ __launch_bounds__(256) void gemm_out(const u16* __restrict__ A,
                                                const u16* __restrict__ B,
                                                float* __restrict__ C) {
    gemm_core(A, B, 2048, blockIdx.x * 64, blockIdx.y * 128,
              [=](int row, int col, float v) {
                  C[(size_t)row * 2048 + col] = v;
              });
}

// ---------------- MQA flash attention, split-K=2, 64 keys/step, swizzled ----
// Q:[2048,2048] bf16 pre-scaled by (1/sqrt(128))*log2e; K:[2048,128]; Vt:[128,2048].
// Block = 128 q x 1 head x 1 key-half; 4 waves x 32 q; 64 keys/step, 16 steps.
// Grid (16,16,2) = 512 blocks, 50KB LDS -> 2 blocks/CU.
// Halved barrier count + 4 independent QK ct-chains + swizzled (conflict-free)
// K/V fragment reads. Deferred softmax: P = exp2(s); fp32 partials + Lsum.
__global__ __launch_bounds__(256) void mqa_attn(const u16* __restrict__ Q,
                                                const u16* __restrict__ Kmat,
                                                const u16* __restrict__ Vt,
                                                float* __restrict__ Oacc0,
                                                float* __restrict__ Oacc1,
                                                float* __restrict__ Lsum) {
    __shared__ __align__(16) u16 Ks[4 * 64 * 32];   // [d-chunk kb4][key64][32 d] 16KB
    __shared__ __align__(16) u16 Vts[2 * 128 * 32]; // [key-chunk kk][d128][32 keys] 16KB
    __shared__ __align__(16) u16 Ps[4][32 * 72];    // per-wave P 32q x 64k, stride 72 18KB
    const int tid  = threadIdx.x;
    const int wave = tid >> 6, lane = tid & 63;
    const int quad = lane >> 4, l16 = lane & 15;
    const int h     = blockIdx.y;
    const int ks    = blockIdx.z;
    const int qbase = blockIdx.x * 128 + wave * 32;
    const int kbase = ks * 1024;

    // Q fragments: 2 mt x 4 d-chunks, resident all kernel
    bf16x8 qf[2][4];
#pragma unroll
    for (int mt = 0; mt < 2; ++mt)
#pragma unroll
        for (int kb4 = 0; kb4 < 4; ++kb4)
            qf[mt][kb4] = *(const bf16x8*)(Q + (size_t)(qbase + mt * 16 + l16) * 2048 +
                                           h * 128 + kb4 * 32 + quad * 8);

    float4_t acc[2][8];
#pragma unroll
    for (int mt = 0; mt < 2; ++mt)
#pragma unroll
        for (int nt = 0; nt < 8; ++nt) acc[mt][nt] = (float4_t){0.f, 0.f, 0.f, 0.f};
    float lsum[8] = {};   // [mt*4 + r]

    u16* pb = Ps[wave];

    for (int s = 0; s < 16; ++s) {
        const int k0 = kbase + s * 64;
        // stage K tile: 1024 slots -> (kb4=slot>>8, key=(slot&255)>>2, chunk swizzled)
#pragma unroll
        for (int i = 0; i < 4; ++i) {
            const int slot = i * 256 + tid;
            const int kb4 = slot >> 8, win = slot & 255;
            const int row = win >> 2;
            GLOAD_LDS16(Kmat + (size_t)(k0 + row) * 128 + kb4 * 32 + sw_st(win & 3, row),
                        &Ks[slot * 8]);
        }
        // stage V tile: 1024 slots -> (kk=slot>>9, d=(slot&511)>>2, chunk swizzled)
#pragma unroll
        for (int i = 0; i < 4; ++i) {
            const int slot = i * 256 + tid;
            const int kk = slot >> 9, win = slot & 511;
            const int row = win >> 2;
            GLOAD_LDS16(Vt + (size_t)row * 2048 + k0 + kk * 32 + sw_st(win & 3, row),
                        &Vts[slot * 8]);
        }
        __syncthreads();

        // ---- S = Q K^T over 64 keys (4 col-tiles of 16); P = exp2(S) ----
#pragma unroll
        for (int ct = 0; ct < 4; ++ct) {
            float4_t s0 = (float4_t){0.f, 0.f, 0.f, 0.f};
            float4_t s1 = (float4_t){0.f, 0.f, 0.f, 0.f};
#pragma unroll
            for (int kb4 = 0; kb4 < 4; ++kb4) {
                const int rw = ct * 16 + l16;
                bf16x8 kf = *(const bf16x8*)&Ks[kb4 * 2048 + rw * 32 + sw_rd(quad, rw)];
                s0 = __builtin_amdgcn_mfma_f32_16x16x32_bf16(qf[0][kb4], kf, s0, 0, 0, 0);
                s1 = __builtin_amdgcn_mfma_f32_16x16x32_bf16(qf[1][kb4], kf, s1, 0, 0, 0);
            }
#pragma unroll
            for (int r = 0; r < 4; ++r) {
                const float e0 = exp2f(s0[r]);
                const float e1 = exp2f(s1[r]);
                lsum[r]     += e0;
                lsum[4 + r] += e1;
                pb[(quad * 4 + r) * 72 + ct * 16 + l16]      = f2bf_hu(e0);
                pb[(16 + quad * 4 + r) * 72 + ct * 16 + l16] = f2bf_hu(e1);
            }
        }
        // P A-frags (own-wave RAW; compiler inserts lgkmcnt wait)
        bf16x8 pa[2][2];
#pragma unroll
        for (int mt = 0; mt < 2; ++mt)
#pragma unroll
            for (int kk = 0; kk < 2; ++kk)
                pa[mt][kk] = *(const bf16x8*)&pb[(mt * 16 + l16) * 72 + kk * 32 + quad * 8];
        // ---- O += P V (32 independent MFMAs) ----
#pragma unroll
        for (int kk = 0; kk < 2; ++kk)
#pragma unroll
            for (int nt = 0; nt < 8; ++nt) {
                const int rw = nt * 16 + l16;
                bf16x8 vf = *(const bf16x8*)&Vts[kk * 4096 + rw * 32 + sw_rd(quad, rw)];
                acc[0][nt] = __builtin_amdgcn_mfma_f32_16x16x32_bf16(pa[0][kk], vf, acc[0][nt], 0, 0, 0);
                acc[1][nt] = __builtin_amdgcn_mfma_f32_16x16x32_bf16(pa[1][kk], vf, acc[1][nt], 0, 0, 0);
            }
        __syncthreads();
    }

    // write unnormalized fp32 partials + per-row sum partials (written once; no init)
    float* __restrict__ Op = ks ? Oacc1 : Oacc0;
#pragma unroll
    for (int mt = 0; mt < 2; ++mt)
#pragma unroll
        for (int r = 0; r < 4; ++r) {
            const int row = qbase + mt * 16 + quad * 4 + r;
            const size_t base = ((size_t)h * 2048 + row) * 128;
            float lrow = lsum[mt * 4 + r];
#pragma unroll
            for (int off = 1; off < 16; off <<= 1) lrow += __shfl_xor(lrow, off);
            if (l16 == 0) Lsum[(size_t)ks * 32768 + h * 2048 + row] = lrow;
#pragma unroll
            for (int nt = 0; nt < 8; ++nt)
                Op[base + nt * 16 + l16] = acc[mt][nt][r];
        }
}

// combine: attn[q][h*128+d] = (O0+O1)/(L0+L1), bf16. One float4 per thread.
__global__ __launch_bounds__(256) void attn_combine(const float* __restrict__ O0,
                                                    const float* __restrict__ O1,
                                                    const float* __restrict__ L,
                                                    u16* __restrict__ attn) {
    const int f = blockIdx.x * 256 + threadIdx.x;  // [0, 1M)
    const int d4 = f & 31, h = (f >> 5) & 15, q = f >> 9;
    const int li = h * 2048 + q;
    const float inv = 1.0f / (L[li] + L[32768 + li]);
    const int oi = li * 32 + d4;
    const float4 a = ((const float4*)O0)[oi];
    const float4 b = ((const float4*)O1)[oi];
    ushort4 r;
    r.x = f2bf((a.x + b.x) * inv);
    r.y = f2bf((a.y + b.y) * inv);
    r.z = f2bf((a.z + b.z) * inv);
    r.w = f2bf((a.w + b.w) * inv);
    ((ushort4*)attn)[f] = r;
}

// ---------------- orchestration ----------------
extern "C" void kernel_launch(void* const* d_in, const int* in_sizes, int n_in,
                              void* d_out, int out_size, void* d_ws, size_t ws_size,
                              hipStream_t stream) {
    const float* x  = (const float*)d_in[0];
    const float* Wq = (const float*)d_in[1];
    const float* Wk = (const float*)d_in[2];
    const float* Wv = (const float*)d_in[3];
    const float* Wo = (const float*)d_in[4];
    float* out = (float*)d_out;

    // Wqb/Wkb/Wvb contiguous: together a 2304x2048 bf16 B matrix for gemm_qkv.
    // Overlays (stream-ordered, deterministic):
    //   Oacc0: [0,16MB)  -- xb+Wqb dead after gemm_qkv
    //   Oacc1: [42,58MB) -- fresh scratch; Lsum at [58,58.5MB). Peak 58.5MB.
    u16* ws   = (u16*)d_ws;
    u16* xb   = ws;                        // 2048x2048 bf16
    u16* Wqb  = xb  + (4 << 20);           // 2048x2048
    u16* Wkb  = Wqb + (4 << 20);           // 128x2048
    u16* Wvb  = Wkb + (256 << 10);         // 128x2048
    u16* Wob  = Wvb + (256 << 10);         // 2048x2048
    u16* qb   = Wob + (4 << 20);           // 2048x2048 (pre-scaled)
    u16* kb   = qb  + (4 << 20);           // 2048x128
    u16* vtb  = kb  + (256 << 10);         // 128x2048 (V^T)
    u16* attn = vtb + (256 << 10);         // 2048x2048 bf16, ends at 42 MB
    float* Oacc0 = (float*)ws;             // 16 MB
    float* Oacc1 = (float*)(attn + (4 << 20));  // 16 MB at [42,58)
    float* Lsum  = Oacc1 + (4 << 20);      // 2 x 32768 fp32

    cast_all<<<12800, 256, 0, stream>>>(x, Wq, Wk, Wv, Wo, xb, Wqb, Wkb, Wvb, Wob);

    gemm_qkv<<<dim3(32, 18), 256, 0, stream>>>(xb, Wqb, qb, kb, vtb);
    mqa_attn<<<dim3(16, 16, 2), 256, 0, stream>>>(qb, kb, vtb, Oacc0, Oacc1, Lsum);
    attn_combine<<<4096, 256, 0, stream>>>(Oacc0, Oacc1, Lsum, attn);
    gemm_out<<<dim3(32, 16), 256, 0, stream>>>(attn, Wob, out);
}